// Round 12
// baseline (102.024 us; speedup 1.0000x reference)
//
#include <hip/hip_runtime.h>
#include <math.h>

#define NTOK 784
#define DIM 128
#define FFD 512

// ========== K1: posw (325 blocks, 32x64) || LN1+qkv (150 blocks, 32 rows) ==========
__global__ __launch_bounds__(256) void posw_qkv3(
    const float* __restrict__ pu, const float* __restrict__ pv, float* __restrict__ W,
    const float* __restrict__ x, const float* __restrict__ g, const float* __restrict__ b,
    const float* __restrict__ wq, const float* __restrict__ wk, const float* __restrict__ wv,
    float* __restrict__ q, float* __restrict__ ek, float* __restrict__ vv,
    int* __restrict__ cnt) {
  __shared__ float smem[12288];  // 48 KB union
  int tid = threadIdx.x;

  if (blockIdx.x == 0 && tid < 32) cnt[tid] = 0;   // reset fold counters each call

  if (blockIdx.x < 325) {
    float (*As)[32] = (float(*)[32])smem;           // [128][32]
    float (*Bs)[64] = (float(*)[64])(smem + 4096);  // [128][64]
    int m0 = (blockIdx.x % 25) * 32, n0 = (blockIdx.x / 25) * 64;
    {
      int r = tid >> 3, kq = (tid & 7) * 16;
      int gm = min(m0 + r, NTOK - 1);
#pragma unroll
      for (int j = 0; j < 4; ++j) {
        float4 a = *(const float4*)&pu[gm * DIM + kq + j * 4];
        As[kq + j * 4 + 0][r] = a.x; As[kq + j * 4 + 1][r] = a.y;
        As[kq + j * 4 + 2][r] = a.z; As[kq + j * 4 + 3][r] = a.w;
      }
      int rb = tid >> 2, kb = (tid & 3) * 32;
      int gn = min(n0 + rb, NTOK - 1);
#pragma unroll
      for (int j = 0; j < 8; ++j) {
        float4 v = *(const float4*)&pv[gn * DIM + kb + j * 4];
        Bs[kb + j * 4 + 0][rb] = v.x; Bs[kb + j * 4 + 1][rb] = v.y;
        Bs[kb + j * 4 + 2][rb] = v.z; Bs[kb + j * 4 + 3][rb] = v.w;
      }
    }
    __syncthreads();
    int tx = tid & 15, ty = tid >> 4;  // 2 rows x 4 cols per thread
    float acc[2][4] = {};
#pragma unroll 8
    for (int kk = 0; kk < DIM; ++kk) {
      float2 a2 = *(const float2*)&As[kk][ty * 2];
      float4 b4 = *(const float4*)&Bs[kk][tx * 4];
      float av[2] = {a2.x, a2.y};
      float bv[4] = {b4.x, b4.y, b4.z, b4.w};
#pragma unroll
      for (int i = 0; i < 2; ++i)
#pragma unroll
        for (int j = 0; j < 4; ++j) acc[i][j] = fmaf(av[i], bv[j], acc[i][j]);
    }
    int c0 = n0 + tx * 4;
    if (c0 + 3 < NTOK) {
#pragma unroll
      for (int i = 0; i < 2; ++i) {
        int gr = m0 + ty * 2 + i;
        if (gr < NTOK) {
          float4 o = {expf(acc[i][0]), expf(acc[i][1]), expf(acc[i][2]), expf(acc[i][3])};
          *(float4*)&W[gr * NTOK + c0] = o;
        }
      }
    }
  } else {
    float (*Xs)[32] = (float(*)[32])smem;            // [128][32]
    float (*Bq)[64] = (float(*)[64])(smem + 4096);   // [64][64]
    float* redS = smem + 8192;
    float* redQ = smem + 8448;
    int bid = blockIdx.x - 325;
    int m0 = (bid % 25) * 32;
    int ct = bid / 25;
    int wsel = ct >> 1;
    int n0 = (ct & 1) * 64;
    const float* B = (wsel == 0) ? wq : (wsel == 1) ? wk : wv;

    if (m0 + 32 <= NTOK) {
#pragma unroll
      for (int it = 0; it < 4; ++it) {
        int idx = it * 256 + tid;
        int c = idx >> 3, j4 = (idx & 7) * 4;
        float4 v = *(const float4*)&x[c * NTOK + m0 + j4];
        Xs[c][j4 + 0] = v.x; Xs[c][j4 + 1] = v.y; Xs[c][j4 + 2] = v.z; Xs[c][j4 + 3] = v.w;
      }
    } else {
#pragma unroll
      for (int it = 0; it < 4; ++it) {
        int idx = it * 256 + tid;
        int c = idx >> 3, j4 = (idx & 7) * 4;
#pragma unroll
        for (int u = 0; u < 4; ++u) {
          int n = min(m0 + j4 + u, NTOK - 1);
          Xs[c][j4 + u] = x[c * NTOK + n];
        }
      }
    }
    __syncthreads();

    int n = tid & 31, grp = tid >> 5;
    float s = 0.f, ss = 0.f;
    for (int c = grp * 16; c < grp * 16 + 16; ++c) { float v = Xs[c][n]; s += v; ss += v * v; }
    redS[grp * 32 + n] = s; redQ[grp * 32 + n] = ss;
    __syncthreads();
    float sum = 0.f, sq = 0.f;
#pragma unroll
    for (int gi = 0; gi < 8; ++gi) { sum += redS[gi * 32 + n]; sq += redQ[gi * 32 + n]; }
    float mu = sum * (1.0f / DIM);
    float var = sq * (1.0f / DIM) - mu * mu;
    float rs = rsqrtf(var + 1e-5f);
    for (int c = grp * 16; c < grp * 16 + 16; ++c)
      Xs[c][n] = (Xs[c][n] - mu) * rs * g[c] + b[c];

    int tx = tid & 15, ty = tid >> 4;
    float acc[2][4] = {};
#pragma unroll
    for (int h = 0; h < 2; ++h) {
      {
        int r = tid >> 2, kq = (tid & 3) * 16;
#pragma unroll
        for (int j = 0; j < 4; ++j) {
          float4 v = *(const float4*)&B[(n0 + r) * DIM + h * 64 + kq + j * 4];
          Bq[kq + j * 4 + 0][r] = v.x; Bq[kq + j * 4 + 1][r] = v.y;
          Bq[kq + j * 4 + 2][r] = v.z; Bq[kq + j * 4 + 3][r] = v.w;
        }
      }
      __syncthreads();
#pragma unroll 4
      for (int kk = 0; kk < 64; ++kk) {
        float2 a2 = *(const float2*)&Xs[h * 64 + kk][ty * 2];
        float4 b4 = *(const float4*)&Bq[kk][tx * 4];
        float av[2] = {a2.x, a2.y};
        float bv[4] = {b4.x, b4.y, b4.z, b4.w};
#pragma unroll
        for (int i = 0; i < 2; ++i)
#pragma unroll
          for (int j = 0; j < 4; ++j) acc[i][j] = fmaf(av[i], bv[j], acc[i][j]);
      }
      __syncthreads();
    }
    int c0 = n0 + tx * 4;
    float* dst = (wsel == 0) ? q : (wsel == 1) ? ek : vv;
#pragma unroll
    for (int i = 0; i < 2; ++i) {
      int gr = m0 + ty * 2 + i;
      if (gr < NTOK) {
        float4 o;
        if (wsel == 0) {
          o.x = 1.0f / (1.0f + expf(-acc[i][0]));
          o.y = 1.0f / (1.0f + expf(-acc[i][1]));
          o.z = 1.0f / (1.0f + expf(-acc[i][2]));
          o.w = 1.0f / (1.0f + expf(-acc[i][3]));
        } else if (wsel == 1) {
          o.x = expf(acc[i][0]); o.y = expf(acc[i][1]);
          o.z = expf(acc[i][2]); o.w = expf(acc[i][3]);
        } else {
          o.x = acc[i][0]; o.y = acc[i][1]; o.z = acc[i][2]; o.w = acc[i][3];
        }
        *(float4*)&dst[gr * DIM + c0] = o;
      }
    }
  }
}

// ========== K2: agg (R8 agg32) + folded gate+proj+LN2 via last-block-done ==========
// grid (25,2,8), 256 thr. 16 blocks share each m-tile (2 d-halves x 8 splits);
// the last to finish does gate+proj+residual+LN2+out-init for its 32 rows.
__global__ __launch_bounds__(256) void agg32_fold(
    const float* __restrict__ W, const float* __restrict__ ek,
    const float* __restrict__ vv, float* __restrict__ nump, float* __restrict__ denp,
    const float* __restrict__ q, const float* __restrict__ wo,
    const float* __restrict__ bo, const float* __restrict__ x,
    const float* __restrict__ g2, const float* __restrict__ b2n,
    const float* __restrict__ b2f, float* __restrict__ fn, float* __restrict__ out,
    int* __restrict__ cnt) {
  __shared__ float smem[15360];   // 60 KB union
  float (*As)[32] = (float(*)[32])smem;            // [96][32]
  float (*Bn)[64] = (float(*)[64])(smem + 3072);   // [96][64]
  float (*Bd)[64] = (float(*)[64])(smem + 9216);   // [96][64]
  int tid = threadIdx.x;
  int m0 = blockIdx.x * 32, d0 = blockIdx.y * 64, sp = blockIdx.z;
  int tx = tid & 15, ty = tid >> 4;         // 2 rows x 4 cols
  int ra = tid >> 3, ka = (tid & 7) * 4;
  int kb = tid >> 3, db = (tid & 7) * 8;
  int gm = min(m0 + ra, NTOK - 1);
  float an[2][4] = {}, ad[2][4] = {};
  int tlo = (sp * 25) / 8, thi = ((sp + 1) * 25) / 8;
  for (int base = tlo; base < thi; base += 3) {
    int nt = min(3, thi - base);
    for (int t = 0; t < nt; ++t) {
      int k0 = (base + t) * 32;
      int lk = t * 32;
      if (k0 + 32 <= NTOK) {
        float4 a = *(const float4*)&W[gm * NTOK + k0 + ka];
        As[lk + ka + 0][ra] = a.x; As[lk + ka + 1][ra] = a.y;
        As[lk + ka + 2][ra] = a.z; As[lk + ka + 3][ra] = a.w;
        int gk = k0 + kb;
        float4 e0 = *(const float4*)&ek[gk * DIM + d0 + db];
        float4 e1 = *(const float4*)&ek[gk * DIM + d0 + db + 4];
        float4 w0 = *(const float4*)&vv[gk * DIM + d0 + db];
        float4 w1_ = *(const float4*)&vv[gk * DIM + d0 + db + 4];
        Bd[lk + kb][db + 0] = e0.x; Bd[lk + kb][db + 1] = e0.y;
        Bd[lk + kb][db + 2] = e0.z; Bd[lk + kb][db + 3] = e0.w;
        Bd[lk + kb][db + 4] = e1.x; Bd[lk + kb][db + 5] = e1.y;
        Bd[lk + kb][db + 6] = e1.z; Bd[lk + kb][db + 7] = e1.w;
        Bn[lk + kb][db + 0] = e0.x * w0.x; Bn[lk + kb][db + 1] = e0.y * w0.y;
        Bn[lk + kb][db + 2] = e0.z * w0.z; Bn[lk + kb][db + 3] = e0.w * w0.w;
        Bn[lk + kb][db + 4] = e1.x * w1_.x; Bn[lk + kb][db + 5] = e1.y * w1_.y;
        Bn[lk + kb][db + 6] = e1.z * w1_.z; Bn[lk + kb][db + 7] = e1.w * w1_.w;
      } else {
#pragma unroll
        for (int j = 0; j < 4; ++j) {
          int gk = k0 + ka + j;
          As[lk + ka + j][ra] = (gk < NTOK) ? W[gm * NTOK + gk] : 0.f;
        }
        int gk = k0 + kb;
        if (gk < NTOK) {
          float4 e0 = *(const float4*)&ek[gk * DIM + d0 + db];
          float4 e1 = *(const float4*)&ek[gk * DIM + d0 + db + 4];
          float4 w0 = *(const float4*)&vv[gk * DIM + d0 + db];
          float4 w1_ = *(const float4*)&vv[gk * DIM + d0 + db + 4];
          Bd[lk + kb][db + 0] = e0.x; Bd[lk + kb][db + 1] = e0.y;
          Bd[lk + kb][db + 2] = e0.z; Bd[lk + kb][db + 3] = e0.w;
          Bd[lk + kb][db + 4] = e1.x; Bd[lk + kb][db + 5] = e1.y;
          Bd[lk + kb][db + 6] = e1.z; Bd[lk + kb][db + 7] = e1.w;
          Bn[lk + kb][db + 0] = e0.x * w0.x; Bn[lk + kb][db + 1] = e0.y * w0.y;
          Bn[lk + kb][db + 2] = e0.z * w0.z; Bn[lk + kb][db + 3] = e0.w * w0.w;
          Bn[lk + kb][db + 4] = e1.x * w1_.x; Bn[lk + kb][db + 5] = e1.y * w1_.y;
          Bn[lk + kb][db + 6] = e1.z * w1_.z; Bn[lk + kb][db + 7] = e1.w * w1_.w;
        } else {
#pragma unroll
          for (int j = 0; j < 8; ++j) { Bd[lk + kb][db + j] = 0.f; Bn[lk + kb][db + j] = 0.f; }
        }
      }
    }
    __syncthreads();
    int nk = nt * 32;
    for (int kk = 0; kk < nk; ++kk) {
      float2 a2 = *(const float2*)&As[kk][ty * 2];
      float4 n4 = *(const float4*)&Bn[kk][tx * 4];
      float4 d4 = *(const float4*)&Bd[kk][tx * 4];
      float av[2] = {a2.x, a2.y};
      float nv[4] = {n4.x, n4.y, n4.z, n4.w};
      float dv[4] = {d4.x, d4.y, d4.z, d4.w};
#pragma unroll
      for (int i = 0; i < 2; ++i)
#pragma unroll
        for (int j = 0; j < 4; ++j) {
          an[i][j] = fmaf(av[i], nv[j], an[i][j]);
          ad[i][j] = fmaf(av[i], dv[j], ad[i][j]);
        }
    }
    __syncthreads();
  }
#pragma unroll
  for (int i = 0; i < 2; ++i) {
    int gr = m0 + ty * 2 + i;
    if (gr < NTOK) {
      float4 on = {an[i][0], an[i][1], an[i][2], an[i][3]};
      float4 od = {ad[i][0], ad[i][1], ad[i][2], ad[i][3]};
      *(float4*)&nump[(sp * NTOK + gr) * DIM + d0 + tx * 4] = on;
      *(float4*)&denp[(sp * NTOK + gr) * DIM + d0 + tx * 4] = od;
    }
  }

  // ---- fold: last of 16 blocks for this m-tile does gate+proj+LN2 ----
  __shared__ int elect;
  __threadfence();                       // publish this block's partials (all threads)
  if (tid == 0) {
    int old = atomicAdd(&cnt[blockIdx.x], 1);
    elect = (old == 15) ? 1 : 0;
  }
  __syncthreads();
  if (!elect) return;
  __threadfence();                       // acquire other blocks' partials

  float (*Att)[33] = (float(*)[33])smem;           // [128][33], 16.9 KB
  float (*Bs)[64] = (float(*)[64])(smem + 4224);   // [128][64], 32 KB
  int row = tid >> 3, lane = tid & 7;    // 32 rows x 8 lanes
  int gn = m0 + row;
  bool live = (gn < NTOK);
  int gc = min(gn, NTOK - 1);

  // gate: attn[row][c] = q * sum(num)/sum(den), k-major into LDS
  {
    int c16 = lane * 16;
#pragma unroll
    for (int j4 = 0; j4 < 4; ++j4) {
      int c = c16 + j4 * 4;
      int basei = gc * DIM + c;
      float4 qv = *(const float4*)&q[basei];
      float4 nv = {0.f, 0.f, 0.f, 0.f}, dv = {0.f, 0.f, 0.f, 0.f};
#pragma unroll
      for (int s = 0; s < 8; ++s) {
        float4 a = *(const float4*)&nump[s * NTOK * DIM + basei];
        float4 d = *(const float4*)&denp[s * NTOK * DIM + basei];
        nv.x += a.x; nv.y += a.y; nv.z += a.z; nv.w += a.w;
        dv.x += d.x; dv.y += d.y; dv.z += d.z; dv.w += d.w;
      }
      Att[c + 0][row] = qv.x * (nv.x / dv.x);
      Att[c + 1][row] = qv.y * (nv.y / dv.y);
      Att[c + 2][row] = qv.z * (nv.z / dv.z);
      Att[c + 3][row] = qv.w * (nv.w / dv.w);
    }
  }
  __syncthreads();

  // proj: two 64-col halves of wo, each staged k-major
  float o[16];
  for (int ch = 0; ch < 2; ++ch) {
    {
      int r = tid >> 2, kq = (tid & 3) * 32;
#pragma unroll
      for (int j = 0; j < 8; ++j) {
        float4 v = *(const float4*)&wo[(ch * 64 + r) * DIM + kq + j * 4];
        Bs[kq + j * 4 + 0][r] = v.x; Bs[kq + j * 4 + 1][r] = v.y;
        Bs[kq + j * 4 + 2][r] = v.z; Bs[kq + j * 4 + 3][r] = v.w;
      }
    }
    __syncthreads();
    int cl = lane * 8;
    float acc[8] = {};
#pragma unroll 4
    for (int k = 0; k < DIM; ++k) {
      float a = Att[k][row];
      float4 b0 = *(const float4*)&Bs[k][cl];
      float4 b1 = *(const float4*)&Bs[k][cl + 4];
      acc[0] = fmaf(a, b0.x, acc[0]); acc[1] = fmaf(a, b0.y, acc[1]);
      acc[2] = fmaf(a, b0.z, acc[2]); acc[3] = fmaf(a, b0.w, acc[3]);
      acc[4] = fmaf(a, b1.x, acc[4]); acc[5] = fmaf(a, b1.y, acc[5]);
      acc[6] = fmaf(a, b1.z, acc[6]); acc[7] = fmaf(a, b1.w, acc[7]);
    }
#pragma unroll
    for (int j = 0; j < 8; ++j) o[ch * 8 + j] = acc[j];
    __syncthreads();
  }

  // bias + residual; LN2 stats over the row (8 lanes x 16 vals)
  float s = 0.f, ss = 0.f;
#pragma unroll
  for (int i = 0; i < 16; ++i) {
    int c = (i >> 3) * 64 + lane * 8 + (i & 7);
    float val = o[i] + bo[c] + x[c * NTOK + gc];
    o[i] = val; s += val; ss += val * val;
  }
#pragma unroll
  for (int off = 1; off < 8; off <<= 1) {
    s += __shfl_xor(s, off);
    ss += __shfl_xor(ss, off);
  }
  float mu = s * (1.0f / DIM);
  float var = ss * (1.0f / DIM) - mu * mu;
  float rs = rsqrtf(var + 1e-5f);

  if (live) {
#pragma unroll
    for (int ch = 0; ch < 2; ++ch) {
      int c0 = ch * 64 + lane * 8;
      float4 f0, f1;
      float* fp0 = &f0.x;
      float* fp1 = &f1.x;
#pragma unroll
      for (int j = 0; j < 4; ++j) {
        int c = c0 + j;
        fp0[j] = (o[ch * 8 + j] - mu) * rs * g2[c] + b2n[c];
        int c2 = c0 + 4 + j;
        fp1[j] = (o[ch * 8 + 4 + j] - mu) * rs * g2[c2] + b2n[c2];
      }
      *(float4*)&fn[gn * DIM + c0] = f0;
      *(float4*)&fn[gn * DIM + c0 + 4] = f1;
#pragma unroll
      for (int j = 0; j < 8; ++j) {
        int c = c0 + j;
        out[c * NTOK + gn] = o[ch * 8 + j] + b2f[c];
      }
    }
  }
}

// ========== K3: ff1(gelu)+ff2 fused, grid (49, 8), 256 thr, atomic accumulate ==========
__global__ __launch_bounds__(256) void ff_fused16(
    const float* __restrict__ fn, const float* __restrict__ w1,
    const float* __restrict__ b1f, const float* __restrict__ w2,
    float* __restrict__ out) {
  __shared__ float Fs[DIM][16];
  __shared__ float W1s[DIM][64];   // reused as W2s[64][128]
  __shared__ float P[16][65];
  int tid = threadIdx.x;
  int m0 = blockIdx.x * 16, f0 = blockIdx.y * 64;

  {
    int r = tid >> 4, kq = (tid & 15) * 8;
#pragma unroll
    for (int j = 0; j < 2; ++j) {
      float4 v = *(const float4*)&fn[(m0 + r) * DIM + kq + j * 4];
      Fs[kq + j * 4 + 0][r] = v.x; Fs[kq + j * 4 + 1][r] = v.y;
      Fs[kq + j * 4 + 2][r] = v.z; Fs[kq + j * 4 + 3][r] = v.w;
    }
    int rw = tid >> 2, kw = (tid & 3) * 32;
#pragma unroll
    for (int j = 0; j < 8; ++j) {
      float4 v = *(const float4*)&w1[(f0 + rw) * DIM + kw + j * 4];
      W1s[kw + j * 4 + 0][rw] = v.x; W1s[kw + j * 4 + 1][rw] = v.y;
      W1s[kw + j * 4 + 2][rw] = v.z; W1s[kw + j * 4 + 3][rw] = v.w;
    }
  }
  __syncthreads();

  int row = tid >> 4, f4 = (tid & 15) * 4;
  float acc1[4] = {};
#pragma unroll 4
  for (int kk = 0; kk < DIM; ++kk) {
    float a = Fs[kk][row];
    float4 b4 = *(const float4*)&W1s[kk][f4];
    acc1[0] = fmaf(a, b4.x, acc1[0]);
    acc1[1] = fmaf(a, b4.y, acc1[1]);
    acc1[2] = fmaf(a, b4.z, acc1[2]);
    acc1[3] = fmaf(a, b4.w, acc1[3]);
  }
  float4 b1v = *(const float4*)&b1f[f0 + f4];
  float bb[4] = {b1v.x, b1v.y, b1v.z, b1v.w};
  float ge[4];
#pragma unroll
  for (int j = 0; j < 4; ++j) {
    float v = acc1[j] + bb[j];
    ge[j] = 0.5f * v * (1.0f + erff(v * 0.70710678118654752f));
  }
  __syncthreads();

#pragma unroll
  for (int j = 0; j < 4; ++j) P[row][f4 + j] = ge[j];
  float* W2s = &W1s[0][0];
  {
    int c = tid >> 1, fq = (tid & 1) * 32;
#pragma unroll
    for (int j = 0; j < 8; ++j) {
      float4 v = *(const float4*)&w2[c * FFD + f0 + fq + j * 4];
      W2s[(fq + j * 4 + 0) * DIM + c] = v.x;
      W2s[(fq + j * 4 + 1) * DIM + c] = v.y;
      W2s[(fq + j * 4 + 2) * DIM + c] = v.z;
      W2s[(fq + j * 4 + 3) * DIM + c] = v.w;
    }
  }
  __syncthreads();

  int r2 = tid & 15, cb = (tid >> 4) * 8;
  float acc2[8] = {};
  for (int f = 0; f < 64; ++f) {
    float pvv = P[r2][f];
    const float* wr = &W2s[f * DIM + cb];
#pragma unroll
    for (int j4 = 0; j4 < 2; ++j4) {
      float4 wv = *(const float4*)&wr[j4 * 4];
      acc2[j4 * 4 + 0] = fmaf(pvv, wv.x, acc2[j4 * 4 + 0]);
      acc2[j4 * 4 + 1] = fmaf(pvv, wv.y, acc2[j4 * 4 + 1]);
      acc2[j4 * 4 + 2] = fmaf(pvv, wv.z, acc2[j4 * 4 + 2]);
      acc2[j4 * 4 + 3] = fmaf(pvv, wv.w, acc2[j4 * 4 + 3]);
    }
  }
#pragma unroll
  for (int j = 0; j < 8; ++j)
    atomicAdd(&out[(cb + j) * NTOK + m0 + r2], acc2[j]);
}

extern "C" void kernel_launch(void* const* d_in, const int* in_sizes, int n_in,
                              void* d_out, int out_size, void* d_ws, size_t ws_size,
                              hipStream_t stream) {
  const float* x   = (const float*)d_in[0];
  const float* wq  = (const float*)d_in[1];
  const float* wk  = (const float*)d_in[2];
  const float* wv  = (const float*)d_in[3];
  const float* wo  = (const float*)d_in[4];
  const float* bo  = (const float*)d_in[5];
  const float* pu  = (const float*)d_in[6];
  const float* pv  = (const float*)d_in[7];
  const float* g1  = (const float*)d_in[8];
  const float* b1n = (const float*)d_in[9];
  const float* g2  = (const float*)d_in[10];
  const float* b2n = (const float*)d_in[11];
  const float* w1  = (const float*)d_in[12];
  const float* b1f = (const float*)d_in[13];
  const float* w2  = (const float*)d_in[14];
  const float* b2f = (const float*)d_in[15];
  float* out = (float*)d_out;

  float* ws = (float*)d_ws;
  float* q    = ws;                 // [784,128]
  float* ek   = ws + 100352;        // [784,128]
  float* vv   = ws + 200704;        // [784,128]
  float* fn   = ws + 301056;        // [784,128]
  float* W    = ws + 401408;        // [784,784]
  float* nump = ws + 1016064;       // [8,784,128]
  float* denp = ws + 1818880;       // [8,784,128]
  int*   cnt  = (int*)(ws + 2621696);  // [25] fold counters

  posw_qkv3<<<475, 256, 0, stream>>>(pu, pv, W, x, g1, b1n, wq, wk, wv, q, ek, vv, cnt);
  agg32_fold<<<dim3(25, 2, 8), 256, 0, stream>>>(W, ek, vv, nump, denp, q, wo, bo, x,
                                                 g2, b2n, b2f, fn, out, cnt);
  ff_fused16<<<dim3(49, 8), 256, 0, stream>>>(fn, w1, b1f, w2, out);
}

// Round 13
// 60.237 us; speedup vs baseline: 1.6937x; 1.6937x over previous
//
#include <hip/hip_runtime.h>
#include <math.h>

#define NTOK 784
#define DIM 128
#define FFD 512
#define NSPLIT 2

// ========== K1: posw (325 blocks, 32x64) || LN1+qkv (150 blocks, 32 rows) ==========
__global__ __launch_bounds__(256) void posw_qkv3(
    const float* __restrict__ pu, const float* __restrict__ pv, float* __restrict__ W,
    const float* __restrict__ x, const float* __restrict__ g, const float* __restrict__ b,
    const float* __restrict__ wq, const float* __restrict__ wk, const float* __restrict__ wv,
    float* __restrict__ q, float* __restrict__ ek, float* __restrict__ vv) {
  __shared__ float smem[12288];  // 48 KB union
  int tid = threadIdx.x;

  if (blockIdx.x < 325) {
    float (*As)[32] = (float(*)[32])smem;           // [128][32]
    float (*Bs)[64] = (float(*)[64])(smem + 4096);  // [128][64]
    int m0 = (blockIdx.x % 25) * 32, n0 = (blockIdx.x / 25) * 64;
    {
      int r = tid >> 3, kq = (tid & 7) * 16;
      int gm = min(m0 + r, NTOK - 1);
#pragma unroll
      for (int j = 0; j < 4; ++j) {
        float4 a = *(const float4*)&pu[gm * DIM + kq + j * 4];
        As[kq + j * 4 + 0][r] = a.x; As[kq + j * 4 + 1][r] = a.y;
        As[kq + j * 4 + 2][r] = a.z; As[kq + j * 4 + 3][r] = a.w;
      }
      int rb = tid >> 2, kb = (tid & 3) * 32;
      int gn = min(n0 + rb, NTOK - 1);
#pragma unroll
      for (int j = 0; j < 8; ++j) {
        float4 v = *(const float4*)&pv[gn * DIM + kb + j * 4];
        Bs[kb + j * 4 + 0][rb] = v.x; Bs[kb + j * 4 + 1][rb] = v.y;
        Bs[kb + j * 4 + 2][rb] = v.z; Bs[kb + j * 4 + 3][rb] = v.w;
      }
    }
    __syncthreads();
    int tx = tid & 15, ty = tid >> 4;  // 2 rows x 4 cols per thread
    float acc[2][4] = {};
#pragma unroll 8
    for (int kk = 0; kk < DIM; ++kk) {
      float2 a2 = *(const float2*)&As[kk][ty * 2];
      float4 b4 = *(const float4*)&Bs[kk][tx * 4];
      float av[2] = {a2.x, a2.y};
      float bv[4] = {b4.x, b4.y, b4.z, b4.w};
#pragma unroll
      for (int i = 0; i < 2; ++i)
#pragma unroll
        for (int j = 0; j < 4; ++j) acc[i][j] = fmaf(av[i], bv[j], acc[i][j]);
    }
    int c0 = n0 + tx * 4;
    if (c0 + 3 < NTOK) {
#pragma unroll
      for (int i = 0; i < 2; ++i) {
        int gr = m0 + ty * 2 + i;
        if (gr < NTOK) {
          float4 o = {expf(acc[i][0]), expf(acc[i][1]), expf(acc[i][2]), expf(acc[i][3])};
          *(float4*)&W[gr * NTOK + c0] = o;
        }
      }
    }
  } else {
    float (*Xs)[32] = (float(*)[32])smem;            // [128][32]
    float (*Bq)[64] = (float(*)[64])(smem + 4096);   // [64][64]
    float* redS = smem + 8192;
    float* redQ = smem + 8448;
    int bid = blockIdx.x - 325;
    int m0 = (bid % 25) * 32;
    int ct = bid / 25;
    int wsel = ct >> 1;
    int n0 = (ct & 1) * 64;
    const float* B = (wsel == 0) ? wq : (wsel == 1) ? wk : wv;

    if (m0 + 32 <= NTOK) {
#pragma unroll
      for (int it = 0; it < 4; ++it) {
        int idx = it * 256 + tid;
        int c = idx >> 3, j4 = (idx & 7) * 4;
        float4 v = *(const float4*)&x[c * NTOK + m0 + j4];
        Xs[c][j4 + 0] = v.x; Xs[c][j4 + 1] = v.y; Xs[c][j4 + 2] = v.z; Xs[c][j4 + 3] = v.w;
      }
    } else {
#pragma unroll
      for (int it = 0; it < 4; ++it) {
        int idx = it * 256 + tid;
        int c = idx >> 3, j4 = (idx & 7) * 4;
#pragma unroll
        for (int u = 0; u < 4; ++u) {
          int n = min(m0 + j4 + u, NTOK - 1);
          Xs[c][j4 + u] = x[c * NTOK + n];
        }
      }
    }
    __syncthreads();

    int n = tid & 31, grp = tid >> 5;
    float s = 0.f, ss = 0.f;
    for (int c = grp * 16; c < grp * 16 + 16; ++c) { float v = Xs[c][n]; s += v; ss += v * v; }
    redS[grp * 32 + n] = s; redQ[grp * 32 + n] = ss;
    __syncthreads();
    float sum = 0.f, sq = 0.f;
#pragma unroll
    for (int gi = 0; gi < 8; ++gi) { sum += redS[gi * 32 + n]; sq += redQ[gi * 32 + n]; }
    float mu = sum * (1.0f / DIM);
    float var = sq * (1.0f / DIM) - mu * mu;
    float rs = rsqrtf(var + 1e-5f);
    for (int c = grp * 16; c < grp * 16 + 16; ++c)
      Xs[c][n] = (Xs[c][n] - mu) * rs * g[c] + b[c];

    int tx = tid & 15, ty = tid >> 4;
    float acc[2][4] = {};
#pragma unroll
    for (int h = 0; h < 2; ++h) {
      {
        int r = tid >> 2, kq = (tid & 3) * 16;
#pragma unroll
        for (int j = 0; j < 4; ++j) {
          float4 v = *(const float4*)&B[(n0 + r) * DIM + h * 64 + kq + j * 4];
          Bq[kq + j * 4 + 0][r] = v.x; Bq[kq + j * 4 + 1][r] = v.y;
          Bq[kq + j * 4 + 2][r] = v.z; Bq[kq + j * 4 + 3][r] = v.w;
        }
      }
      __syncthreads();
#pragma unroll 4
      for (int kk = 0; kk < 64; ++kk) {
        float2 a2 = *(const float2*)&Xs[h * 64 + kk][ty * 2];
        float4 b4 = *(const float4*)&Bq[kk][tx * 4];
        float av[2] = {a2.x, a2.y};
        float bv[4] = {b4.x, b4.y, b4.z, b4.w};
#pragma unroll
        for (int i = 0; i < 2; ++i)
#pragma unroll
          for (int j = 0; j < 4; ++j) acc[i][j] = fmaf(av[i], bv[j], acc[i][j]);
      }
      __syncthreads();
    }
    int c0 = n0 + tx * 4;
    float* dst = (wsel == 0) ? q : (wsel == 1) ? ek : vv;
#pragma unroll
    for (int i = 0; i < 2; ++i) {
      int gr = m0 + ty * 2 + i;
      if (gr < NTOK) {
        float4 o;
        if (wsel == 0) {
          o.x = 1.0f / (1.0f + expf(-acc[i][0]));
          o.y = 1.0f / (1.0f + expf(-acc[i][1]));
          o.z = 1.0f / (1.0f + expf(-acc[i][2]));
          o.w = 1.0f / (1.0f + expf(-acc[i][3]));
        } else if (wsel == 1) {
          o.x = expf(acc[i][0]); o.y = expf(acc[i][1]);
          o.z = expf(acc[i][2]); o.w = expf(acc[i][3]);
        } else {
          o.x = acc[i][0]; o.y = acc[i][1]; o.z = acc[i][2]; o.w = acc[i][3];
        }
        *(float4*)&dst[gr * DIM + c0] = o;
      }
    }
  }
}

// ========== K2: agg, split-2, 32-row tiles, grid (25,2,2), 256 thr ==========
__global__ __launch_bounds__(256) void agg32s2(
    const float* __restrict__ W, const float* __restrict__ ek,
    const float* __restrict__ vv, float* __restrict__ nump, float* __restrict__ denp) {
  __shared__ float As[96][32];
  __shared__ float Bn[96][64];
  __shared__ float Bd[96][64];
  int tid = threadIdx.x;
  int m0 = blockIdx.x * 32, d0 = blockIdx.y * 64, sp = blockIdx.z;
  int tx = tid & 15, ty = tid >> 4;         // 2 rows x 4 cols
  int ra = tid >> 3, ka = (tid & 7) * 4;
  int kb = tid >> 3, db = (tid & 7) * 8;
  int gm = min(m0 + ra, NTOK - 1);
  float an[2][4] = {}, ad[2][4] = {};
  int tlo = (sp * 25) / NSPLIT, thi = ((sp + 1) * 25) / NSPLIT;
  for (int base = tlo; base < thi; base += 3) {
    int nt = min(3, thi - base);
    for (int t = 0; t < nt; ++t) {
      int k0 = (base + t) * 32;
      int lk = t * 32;
      if (k0 + 32 <= NTOK) {
        float4 a = *(const float4*)&W[gm * NTOK + k0 + ka];
        As[lk + ka + 0][ra] = a.x; As[lk + ka + 1][ra] = a.y;
        As[lk + ka + 2][ra] = a.z; As[lk + ka + 3][ra] = a.w;
        int gk = k0 + kb;
        float4 e0 = *(const float4*)&ek[gk * DIM + d0 + db];
        float4 e1 = *(const float4*)&ek[gk * DIM + d0 + db + 4];
        float4 w0 = *(const float4*)&vv[gk * DIM + d0 + db];
        float4 w1_ = *(const float4*)&vv[gk * DIM + d0 + db + 4];
        Bd[lk + kb][db + 0] = e0.x; Bd[lk + kb][db + 1] = e0.y;
        Bd[lk + kb][db + 2] = e0.z; Bd[lk + kb][db + 3] = e0.w;
        Bd[lk + kb][db + 4] = e1.x; Bd[lk + kb][db + 5] = e1.y;
        Bd[lk + kb][db + 6] = e1.z; Bd[lk + kb][db + 7] = e1.w;
        Bn[lk + kb][db + 0] = e0.x * w0.x; Bn[lk + kb][db + 1] = e0.y * w0.y;
        Bn[lk + kb][db + 2] = e0.z * w0.z; Bn[lk + kb][db + 3] = e0.w * w0.w;
        Bn[lk + kb][db + 4] = e1.x * w1_.x; Bn[lk + kb][db + 5] = e1.y * w1_.y;
        Bn[lk + kb][db + 6] = e1.z * w1_.z; Bn[lk + kb][db + 7] = e1.w * w1_.w;
      } else {
#pragma unroll
        for (int j = 0; j < 4; ++j) {
          int gk = k0 + ka + j;
          As[lk + ka + j][ra] = (gk < NTOK) ? W[gm * NTOK + gk] : 0.f;
        }
        int gk = k0 + kb;
        if (gk < NTOK) {
          float4 e0 = *(const float4*)&ek[gk * DIM + d0 + db];
          float4 e1 = *(const float4*)&ek[gk * DIM + d0 + db + 4];
          float4 w0 = *(const float4*)&vv[gk * DIM + d0 + db];
          float4 w1_ = *(const float4*)&vv[gk * DIM + d0 + db + 4];
          Bd[lk + kb][db + 0] = e0.x; Bd[lk + kb][db + 1] = e0.y;
          Bd[lk + kb][db + 2] = e0.z; Bd[lk + kb][db + 3] = e0.w;
          Bd[lk + kb][db + 4] = e1.x; Bd[lk + kb][db + 5] = e1.y;
          Bd[lk + kb][db + 6] = e1.z; Bd[lk + kb][db + 7] = e1.w;
          Bn[lk + kb][db + 0] = e0.x * w0.x; Bn[lk + kb][db + 1] = e0.y * w0.y;
          Bn[lk + kb][db + 2] = e0.z * w0.z; Bn[lk + kb][db + 3] = e0.w * w0.w;
          Bn[lk + kb][db + 4] = e1.x * w1_.x; Bn[lk + kb][db + 5] = e1.y * w1_.y;
          Bn[lk + kb][db + 6] = e1.z * w1_.z; Bn[lk + kb][db + 7] = e1.w * w1_.w;
        } else {
#pragma unroll
          for (int j = 0; j < 8; ++j) { Bd[lk + kb][db + j] = 0.f; Bn[lk + kb][db + j] = 0.f; }
        }
      }
    }
    __syncthreads();
    int nk = nt * 32;
    for (int kk = 0; kk < nk; ++kk) {
      float2 a2 = *(const float2*)&As[kk][ty * 2];
      float4 n4 = *(const float4*)&Bn[kk][tx * 4];
      float4 d4 = *(const float4*)&Bd[kk][tx * 4];
      float av[2] = {a2.x, a2.y};
      float nv[4] = {n4.x, n4.y, n4.z, n4.w};
      float dv[4] = {d4.x, d4.y, d4.z, d4.w};
#pragma unroll
      for (int i = 0; i < 2; ++i)
#pragma unroll
        for (int j = 0; j < 4; ++j) {
          an[i][j] = fmaf(av[i], nv[j], an[i][j]);
          ad[i][j] = fmaf(av[i], dv[j], ad[i][j]);
        }
    }
    __syncthreads();
  }
#pragma unroll
  for (int i = 0; i < 2; ++i) {
    int gr = m0 + ty * 2 + i;
    if (gr < NTOK) {
      float4 on = {an[i][0], an[i][1], an[i][2], an[i][3]};
      float4 od = {ad[i][0], ad[i][1], ad[i][2], ad[i][3]};
      *(float4*)&nump[(sp * NTOK + gr) * DIM + d0 + tx * 4] = on;
      *(float4*)&denp[(sp * NTOK + gr) * DIM + d0 + tx * 4] = od;
    }
  }
}

// ========== K3: gate + O-proj + residual + LN2 + out-init, 98 blocks x 256 thr ==========
__global__ __launch_bounds__(256) void gate_proj_ln(
    const float* __restrict__ q, const float* __restrict__ nump,
    const float* __restrict__ denp, const float* __restrict__ wo,
    const float* __restrict__ bo, const float* __restrict__ x,
    const float* __restrict__ g2, const float* __restrict__ b2n,
    const float* __restrict__ b2f, float* __restrict__ fn, float* __restrict__ out) {
  __shared__ float At[DIM][9];     // attn tile k-major, 8 rows
  __shared__ float Bs[DIM][DIM];   // full wo, k-major
  int tid = threadIdx.x;
  int m0 = blockIdx.x * 8;         // 98*8 = 784

  {
    int nn = tid >> 5, c4 = (tid & 31) * 4;
    int base = (m0 + nn) * DIM + c4;
    float4 qv = *(const float4*)&q[base];
    float4 nv = {0.f, 0.f, 0.f, 0.f}, dv = {0.f, 0.f, 0.f, 0.f};
#pragma unroll
    for (int s = 0; s < NSPLIT; ++s) {
      float4 a = *(const float4*)&nump[s * NTOK * DIM + base];
      float4 d = *(const float4*)&denp[s * NTOK * DIM + base];
      nv.x += a.x; nv.y += a.y; nv.z += a.z; nv.w += a.w;
      dv.x += d.x; dv.y += d.y; dv.z += d.z; dv.w += d.w;
    }
    At[c4 + 0][nn] = qv.x * (nv.x / dv.x);
    At[c4 + 1][nn] = qv.y * (nv.y / dv.y);
    At[c4 + 2][nn] = qv.z * (nv.z / dv.z);
    At[c4 + 3][nn] = qv.w * (nv.w / dv.w);
  }
  {
    int r = tid >> 1, kq = (tid & 1) * 64;
#pragma unroll
    for (int j = 0; j < 16; ++j) {
      float4 v = *(const float4*)&wo[r * DIM + kq + j * 4];
      Bs[kq + j * 4 + 0][r] = v.x; Bs[kq + j * 4 + 1][r] = v.y;
      Bs[kq + j * 4 + 2][r] = v.z; Bs[kq + j * 4 + 3][r] = v.w;
    }
  }
  __syncthreads();

  int ty = tid >> 5, tx = tid & 31;
  float acc[4] = {0.f, 0.f, 0.f, 0.f};
#pragma unroll 4
  for (int kk = 0; kk < DIM; ++kk) {
    float a = At[kk][ty];
    float4 b4 = *(const float4*)&Bs[kk][tx * 4];
    acc[0] = fmaf(a, b4.x, acc[0]);
    acc[1] = fmaf(a, b4.y, acc[1]);
    acc[2] = fmaf(a, b4.z, acc[2]);
    acc[3] = fmaf(a, b4.w, acc[3]);
  }
  int gn = m0 + ty;
  int c0 = tx * 4;
  float4 bias = *(const float4*)&bo[c0];
  float o0 = acc[0] + bias.x + x[(c0 + 0) * NTOK + gn];
  float o1 = acc[1] + bias.y + x[(c0 + 1) * NTOK + gn];
  float o2 = acc[2] + bias.z + x[(c0 + 2) * NTOK + gn];
  float o3 = acc[3] + bias.w + x[(c0 + 3) * NTOK + gn];

  float4 bf = *(const float4*)&b2f[c0];
  out[(c0 + 0) * NTOK + gn] = o0 + bf.x;
  out[(c0 + 1) * NTOK + gn] = o1 + bf.y;
  out[(c0 + 2) * NTOK + gn] = o2 + bf.z;
  out[(c0 + 3) * NTOK + gn] = o3 + bf.w;

  float s = o0 + o1 + o2 + o3;
  float ss = o0 * o0 + o1 * o1 + o2 * o2 + o3 * o3;
#pragma unroll
  for (int off = 1; off < 32; off <<= 1) {
    s += __shfl_xor(s, off);
    ss += __shfl_xor(ss, off);
  }
  float mu = s * (1.0f / DIM);
  float var = ss * (1.0f / DIM) - mu * mu;
  float rs = rsqrtf(var + 1e-5f);
  float4 gg = *(const float4*)&g2[c0];
  float4 bb = *(const float4*)&b2n[c0];
  float4 f;
  f.x = (o0 - mu) * rs * gg.x + bb.x;
  f.y = (o1 - mu) * rs * gg.y + bb.y;
  f.z = (o2 - mu) * rs * gg.z + bb.z;
  f.w = (o3 - mu) * rs * gg.w + bb.w;
  *(float4*)&fn[gn * DIM + c0] = f;
}

// ========== K4: ff1(gelu)+ff2 fused, grid (49, 8), 256 thr, atomic accumulate ==========
__global__ __launch_bounds__(256) void ff_fused16(
    const float* __restrict__ fn, const float* __restrict__ w1,
    const float* __restrict__ b1f, const float* __restrict__ w2,
    float* __restrict__ out) {
  __shared__ float Fs[DIM][16];
  __shared__ float W1s[DIM][64];   // reused as W2s[64][128]
  __shared__ float P[16][65];
  int tid = threadIdx.x;
  int m0 = blockIdx.x * 16, f0 = blockIdx.y * 64;

  {
    int r = tid >> 4, kq = (tid & 15) * 8;
#pragma unroll
    for (int j = 0; j < 2; ++j) {
      float4 v = *(const float4*)&fn[(m0 + r) * DIM + kq + j * 4];
      Fs[kq + j * 4 + 0][r] = v.x; Fs[kq + j * 4 + 1][r] = v.y;
      Fs[kq + j * 4 + 2][r] = v.z; Fs[kq + j * 4 + 3][r] = v.w;
    }
    int rw = tid >> 2, kw = (tid & 3) * 32;
#pragma unroll
    for (int j = 0; j < 8; ++j) {
      float4 v = *(const float4*)&w1[(f0 + rw) * DIM + kw + j * 4];
      W1s[kw + j * 4 + 0][rw] = v.x; W1s[kw + j * 4 + 1][rw] = v.y;
      W1s[kw + j * 4 + 2][rw] = v.z; W1s[kw + j * 4 + 3][rw] = v.w;
    }
  }
  __syncthreads();

  int row = tid >> 4, f4 = (tid & 15) * 4;
  float acc1[4] = {};
#pragma unroll 4
  for (int kk = 0; kk < DIM; ++kk) {
    float a = Fs[kk][row];
    float4 b4 = *(const float4*)&W1s[kk][f4];
    acc1[0] = fmaf(a, b4.x, acc1[0]);
    acc1[1] = fmaf(a, b4.y, acc1[1]);
    acc1[2] = fmaf(a, b4.z, acc1[2]);
    acc1[3] = fmaf(a, b4.w, acc1[3]);
  }
  float4 b1v = *(const float4*)&b1f[f0 + f4];
  float bb[4] = {b1v.x, b1v.y, b1v.z, b1v.w};
  float ge[4];
#pragma unroll
  for (int j = 0; j < 4; ++j) {
    float v = acc1[j] + bb[j];
    ge[j] = 0.5f * v * (1.0f + erff(v * 0.70710678118654752f));
  }
  __syncthreads();

#pragma unroll
  for (int j = 0; j < 4; ++j) P[row][f4 + j] = ge[j];
  float* W2s = &W1s[0][0];
  {
    int c = tid >> 1, fq = (tid & 1) * 32;
#pragma unroll
    for (int j = 0; j < 8; ++j) {
      float4 v = *(const float4*)&w2[c * FFD + f0 + fq + j * 4];
      W2s[(fq + j * 4 + 0) * DIM + c] = v.x;
      W2s[(fq + j * 4 + 1) * DIM + c] = v.y;
      W2s[(fq + j * 4 + 2) * DIM + c] = v.z;
      W2s[(fq + j * 4 + 3) * DIM + c] = v.w;
    }
  }
  __syncthreads();

  int r2 = tid & 15, cb = (tid >> 4) * 8;
  float acc2[8] = {};
  for (int f = 0; f < 64; ++f) {
    float pvv = P[r2][f];
    const float* wr = &W2s[f * DIM + cb];
#pragma unroll
    for (int j4 = 0; j4 < 2; ++j4) {
      float4 wv = *(const float4*)&wr[j4 * 4];
      acc2[j4 * 4 + 0] = fmaf(pvv, wv.x, acc2[j4 * 4 + 0]);
      acc2[j4 * 4 + 1] = fmaf(pvv, wv.y, acc2[j4 * 4 + 1]);
      acc2[j4 * 4 + 2] = fmaf(pvv, wv.z, acc2[j4 * 4 + 2]);
      acc2[j4 * 4 + 3] = fmaf(pvv, wv.w, acc2[j4 * 4 + 3]);
    }
  }
#pragma unroll
  for (int j = 0; j < 8; ++j)
    atomicAdd(&out[(cb + j) * NTOK + m0 + r2], acc2[j]);
}

extern "C" void kernel_launch(void* const* d_in, const int* in_sizes, int n_in,
                              void* d_out, int out_size, void* d_ws, size_t ws_size,
                              hipStream_t stream) {
  const float* x   = (const float*)d_in[0];
  const float* wq  = (const float*)d_in[1];
  const float* wk  = (const float*)d_in[2];
  const float* wv  = (const float*)d_in[3];
  const float* wo  = (const float*)d_in[4];
  const float* bo  = (const float*)d_in[5];
  const float* pu  = (const float*)d_in[6];
  const float* pv  = (const float*)d_in[7];
  const float* g1  = (const float*)d_in[8];
  const float* b1n = (const float*)d_in[9];
  const float* g2  = (const float*)d_in[10];
  const float* b2n = (const float*)d_in[11];
  const float* w1  = (const float*)d_in[12];
  const float* b1f = (const float*)d_in[13];
  const float* w2  = (const float*)d_in[14];
  const float* b2f = (const float*)d_in[15];
  float* out = (float*)d_out;

  float* ws = (float*)d_ws;
  float* q    = ws;                 // [784,128]
  float* ek   = ws + 100352;        // [784,128]
  float* vv   = ws + 200704;        // [784,128]
  float* fn   = ws + 301056;        // [784,128]
  float* W    = ws + 401408;        // [784,784]
  float* nump = ws + 1016064;       // [2,784,128]
  float* denp = ws + 1216768;       // [2,784,128]

  posw_qkv3<<<475, 256, 0, stream>>>(pu, pv, W, x, g1, b1n, wq, wk, wv, q, ek, vv);
  agg32s2<<<dim3(25, 2, NSPLIT), 256, 0, stream>>>(W, ek, vv, nump, denp);
  gate_proj_ln<<<98, 256, 0, stream>>>(q, nump, denp, wo, bo, x, g2, b2n, b2f, fn, out);
  ff_fused16<<<dim3(49, 8), 256, 0, stream>>>(fn, w1, b1f, w2, out);
}